// Round 6
// baseline (352.360 us; speedup 1.0000x reference)
//
#include <hip/hip_runtime.h>
#include <hip/hip_bf16.h>
#include <math.h>

// Problem dims (fixed)
constexpr int TDIM = 256;   // sequence length t
constexpr int CDIM = 256;   // channels C
constexpr int NH   = 4;     // heads
constexpr int DHS  = 64;    // head size
constexpr int FHID = 1024;  // ffn hidden
constexpr int NV   = 8000;  // vocab
constexpr int NB   = 2;     // batch

typedef __attribute__((ext_vector_type(8))) short bf16x8;
typedef __attribute__((ext_vector_type(4))) float f32x4;
typedef __attribute__((ext_vector_type(2))) float f32x2;
typedef __attribute__((ext_vector_type(4))) unsigned int uint4v;

__device__ __forceinline__ float gelu_f(float x) {
    return 0.5f * x * (1.0f + erff(x * 0.70710678118654752440f));
}

// packed tanh-form gelu on 2 lanes: x*E/(E+1), E=exp2(x*(kA+kB*x^2))
__device__ __forceinline__ f32x2 gelu2(f32x2 x) {
    constexpr float kA = 2.0f * 1.4426950408889634f * 0.7978845608028654f;
    constexpr float kB = kA * 0.044715f;
    f32x2 arg = x * (kA + kB * (x * x));
    arg.x = fminf(arg.x, 120.f);
    arg.y = fminf(arg.y, 120.f);
    float e0 = exp2f(arg.x), e1 = exp2f(arg.y);
    f32x2 num; num.x = x.x * e0; num.y = x.y * e1;
    f32x2 den; den.x = __builtin_amdgcn_rcpf(e0 + 1.f); den.y = __builtin_amdgcn_rcpf(e1 + 1.f);
    return num * den;
}

__device__ __forceinline__ unsigned short f2bf(float f) {
    unsigned int u = __float_as_uint(f);
    unsigned int r = (u + 0x7FFF + ((u >> 16) & 1)) >> 16;   // RNE
    return (unsigned short)r;
}

// ---------------- merged weight transpose+cast (all 6 tensors, one launch) ----------
__global__ __launch_bounds__(256) void k_tcast_all(
    const float* __restrict__ head_w, const float* __restrict__ att_w1,
    const float* __restrict__ ff_w1, const float* __restrict__ ff_w2,
    const float* __restrict__ val_w, const float* __restrict__ proj_w,
    unsigned short* __restrict__ wT, unsigned short* __restrict__ W1r,
    unsigned short* __restrict__ Wff1, unsigned short* __restrict__ Wff2,
    unsigned short* __restrict__ Wv, unsigned short* __restrict__ Wproj)
{
    int q = blockIdx.x;
    const float* src; unsigned short* dst; int R, C, tx, ty;
    if (q < 2000)      { src = head_w; dst = wT; R = 256; C = 8000; tx = q % 250; ty = q / 250; }
    else if (q < 3024) { int u = q - 2000, s = u >> 7, v = u & 127;
        src = att_w1 + (size_t)s * 512 * 256; dst = W1r + (size_t)s * 512 * 256;
        R = 512; C = 256; tx = v & 7; ty = v >> 3; }
    else if (q < 3536) { int u = q - 3024, s = u >> 8, v = u & 255;
        src = ff_w1 + (size_t)s * 256 * 1024; dst = Wff1 + (size_t)s * 256 * 1024;
        R = 256; C = 1024; tx = v & 31; ty = v >> 5; }
    else if (q < 4048) { int u = q - 3536, s = u >> 8, v = u & 255;
        src = ff_w2 + (size_t)s * 1024 * 256; dst = Wff2 + (size_t)s * 1024 * 256;
        R = 1024; C = 256; tx = v & 7; ty = v >> 3; }
    else if (q < 4176) { int u = q - 4048, s = u >> 4, v = u & 15;
        src = val_w + (size_t)s * 256 * 64; dst = Wv + (size_t)s * 256 * 64;
        R = 256; C = 64; tx = v & 1; ty = v >> 1; }
    else { int u = q - 4176, s = u >> 6, v = u & 63;
        src = proj_w + (size_t)s * 256 * 256; dst = Wproj + (size_t)s * 256 * 256;
        R = 256; C = 256; tx = v & 7; ty = v >> 3; }
    __shared__ float tile[32][33];
    int c0 = tx * 32, r0 = ty * 32, t = threadIdx.x;
    #pragma unroll
    for (int e = 0; e < 4; ++e) {
        int lin = e * 256 + t; int rr = lin >> 5, cc = lin & 31;
        tile[rr][cc] = src[(size_t)(r0 + rr) * C + c0 + cc];
    }
    __syncthreads();
    #pragma unroll
    for (int e = 0; e < 4; ++e) {
        int lin = e * 256 + t; int cc = lin >> 5, rr = lin & 31;
        dst[(size_t)(c0 + cc) * R + r0 + rr] = f2bf(tile[rr][cc]);
    }
}

// merged embed + pe. grid 512, block 512.
// bid<256: embed rows 2bid,2bid+1. bid>=256: pe row d=bid-256.
__global__ __launch_bounds__(512) void k_pre(
    const int* __restrict__ idx, const float* __restrict__ tok_emb,
    const float* __restrict__ pos_table, const float* __restrict__ pos_w1,
    const float* __restrict__ pos_w2, const float* __restrict__ pos_b2,
    const float* __restrict__ g, const float* __restrict__ bb,
    float* __restrict__ x, unsigned short* __restrict__ x_bf,
    unsigned short* __restrict__ ped_bf)
{
    int bid = blockIdx.x;
    int t = threadIdx.x;           // 512
    if (bid < 256) {
        int r = bid * 2 + (t >> 8);
        int c = t & 255;
        int tok = idx[r];
        float v = tok_emb[(size_t)tok * CDIM + c];
        x[r * CDIM + c] = v;
        x_bf[r * CDIM + c] = f2bf(v);
        return;
    }
    int d = bid - 256;
    __shared__ float xs[CDIM];
    __shared__ float hs[512];
    __shared__ float red[512];
    if (t < CDIM) xs[t] = pos_table[d * CDIM + t];
    __syncthreads();
    float acc = 0.f;
    for (int c = 0; c < CDIM; ++c) acc += xs[c] * pos_w1[(size_t)c * 512 + t];
    hs[t] = gelu_f(acc);
    __syncthreads();
    float acc2 = pos_b2[t];
    for (int z = 0; z < 512; ++z) acc2 += hs[z] * pos_w2[(size_t)z * 512 + t];
    red[t] = acc2; __syncthreads();
    for (int s = 256; s > 0; s >>= 1) { if (t < s) red[t] += red[t + s]; __syncthreads(); }
    float mean = red[0] * (1.f / 512.f); __syncthreads();
    float dv = acc2 - mean;
    red[t] = dv * dv; __syncthreads();
    for (int s = 256; s > 0; s >>= 1) { if (t < s) red[t] += red[t + s]; __syncthreads(); }
    float r = rsqrtf(red[0] * (1.f / 512.f) + 1e-5f);
    ped_bf[d * 512 + t] = f2bf(dv * r * g[t] + bb[t]);
}

// ---------------- shared bf16 MFMA 64x64-tile core, K-chunk 128 (32KB LDS) ----------
__device__ __forceinline__ void gemm64_core(
    const unsigned short* __restrict__ A, int lda,
    const unsigned short* __restrict__ B, int ldb,
    int kLen, int t, f32x4 acc[2][2],
    unsigned short* __restrict__ A_lds, unsigned short* __restrict__ B_lds)
{
    int lane = t & 63;
    int w = t >> 6;
    int wm = (w >> 1) * 32, wn = (w & 1) * 32;
    int l15 = lane & 15;
    int lk = (lane >> 4) * 8;
    for (int kc = 0; kc < kLen; kc += 128) {
        #pragma unroll
        for (int it = 0; it < 4; ++it) {
            int chunk = it * 256 + t;       // 1024 x 16B chunks
            int row = chunk >> 4;           // 16 chunks per 128-col row
            int c16 = chunk & 15;
            uint4v va = *(const uint4v*)(A + (size_t)row * lda + kc + c16 * 8);
            uint4v vb = *(const uint4v*)(B + (size_t)row * ldb + kc + c16 * 8);
            int lin = row * 256 + c16 * 16;
            int phys = lin ^ ((row & 7) << 4);
            *(uint4v*)((char*)A_lds + phys) = va;
            *(uint4v*)((char*)B_lds + phys) = vb;
        }
        __syncthreads();
        #pragma unroll
        for (int ks = 0; ks < 4; ++ks) {
            int kb = ks * 32 + lk;
            bf16x8 a[2], b[2];
            #pragma unroll
            for (int f = 0; f < 2; ++f) {
                int mrow = wm + f * 16 + l15;
                int lina = mrow * 256 + kb * 2;
                a[f] = *(const bf16x8*)((const char*)A_lds + (lina ^ ((mrow & 7) << 4)));
                int nrow = wn + f * 16 + l15;
                int linb = nrow * 256 + kb * 2;
                b[f] = *(const bf16x8*)((const char*)B_lds + (linb ^ ((nrow & 7) << 4)));
            }
            acc[0][0] = __builtin_amdgcn_mfma_f32_16x16x32_bf16(a[0], b[0], acc[0][0], 0, 0, 0);
            acc[0][1] = __builtin_amdgcn_mfma_f32_16x16x32_bf16(a[0], b[1], acc[0][1], 0, 0, 0);
            acc[1][0] = __builtin_amdgcn_mfma_f32_16x16x32_bf16(a[1], b[0], acc[1][0], 0, 0, 0);
            acc[1][1] = __builtin_amdgcn_mfma_f32_16x16x32_bf16(a[1], b[1], acc[1][1], 0, 0, 0);
        }
        __syncthreads();
    }
}

// merged QKV: bid<256 -> pq GEMM; 256..319 -> r GEMM; 320..351 -> v GEMM
__global__ __launch_bounds__(256) void k_qkv(
    const unsigned short* __restrict__ x_bf,   // [512][256]
    const unsigned short* __restrict__ ped_bf, // [256][512]
    const unsigned short* __restrict__ W1r,    // [L][1024][512]
    const unsigned short* __restrict__ Wv,     // [L*4][64][256]
    float* __restrict__ PT, float* __restrict__ Qb, float* __restrict__ RT,
    float* __restrict__ vbuf, int l)
{
    __shared__ unsigned short A_lds[64 * 128];
    __shared__ unsigned short B_lds[64 * 128];
    int t = threadIdx.x;
    int bid = blockIdx.x;
    int lane = t & 63, w = t >> 6;
    int wm = (w >> 1) * 32, wn = (w & 1) * 32;
    int l15 = lane & 15;
    f32x4 acc[2][2] = {};
    if (bid < 256) {           // pq: out[512,2048] = x_bf @ W1
        int r0 = (bid & 7) * 64;
        int n0 = (bid >> 3) * 64;
        int h = n0 >> 9, isQ = (n0 >> 8) & 1;
        const unsigned short* Bp = W1r + (size_t)l * 1024 * 512
                                 + (size_t)(h * 256 + (n0 & 255)) * 512 + isQ * 256;
        gemm64_core(x_bf + (size_t)r0 * 256, 256, Bp, 512, 256, t, acc, A_lds, B_lds);
        #pragma unroll
        for (int fm = 0; fm < 2; ++fm)
        #pragma unroll
        for (int fn = 0; fn < 2; ++fn) {
            int col = n0 + wn + fn * 16 + l15;
            int c = col & 255;
            #pragma unroll
            for (int r = 0; r < 4; ++r) {
                int row = r0 + wm + fm * 16 + (lane >> 4) * 4 + r;
                int b = row >> 8, ij = row & 255;
                if (isQ) Qb[((b * TDIM + ij) * NH + h) * CDIM + c] = acc[fm][fn][r];
                else     PT[((size_t)(b * NH + h) * CDIM + c) * TDIM + ij] = acc[fm][fn][r];
            }
        }
    } else if (bid < 320) {    // r: out[256 d, 1024 (h,c)] = ped_bf @ W1r^T
        int u = bid - 256;
        int r0 = (u & 3) * 64;
        int n0 = (u >> 2) * 64;
        const unsigned short* Bp = W1r + (size_t)l * 1024 * 512 + (size_t)n0 * 512;
        gemm64_core(ped_bf + (size_t)r0 * 512, 512, Bp, 512, 512, t, acc, A_lds, B_lds);
        #pragma unroll
        for (int fm = 0; fm < 2; ++fm)
        #pragma unroll
        for (int fn = 0; fn < 2; ++fn) {
            int col = n0 + wn + fn * 16 + l15;
            #pragma unroll
            for (int r = 0; r < 4; ++r) {
                int d = r0 + wm + fm * 16 + (lane >> 4) * 4 + r;
                RT[(size_t)col * TDIM + d] = acc[fm][fn][r];
            }
        }
    } else {                   // v: out[512 (b,j), 256 (h,d)] = x_bf @ Wv^T -> vbuf f32
        int u = bid - 320;
        int r0 = (u & 7) * 64;
        int n0 = (u >> 3) * 64;
        int h = n0 >> 6;
        const unsigned short* Bp = Wv + ((size_t)l * NH + h) * DHS * CDIM;
        gemm64_core(x_bf + (size_t)r0 * 256, 256, Bp, 256, 256, t, acc, A_lds, B_lds);
        #pragma unroll
        for (int fm = 0; fm < 2; ++fm)
        #pragma unroll
        for (int fn = 0; fn < 2; ++fn) {
            int col = n0 + wn + fn * 16 + l15;
            int d = col & 63;
            #pragma unroll
            for (int r = 0; r < 4; ++r) {
                int row = r0 + wm + fm * 16 + (lane >> 4) * 4 + r;
                int b = row >> 8, j = row & 255;
                vbuf[((size_t)(b * NH + h) * TDIM + j) * DHS + d] = acc[fm][fn][r];
            }
        }
    }
}

// wei + softmax + PV fused. i-tile 4, 4-way c-split, 1024 threads.
// Software-pipelined p/r loads; PV against L2-resident vbuf; writes attn_bf.
__global__ __launch_bounds__(1024, 8) void k_wei(
    const float* __restrict__ PT, const float* __restrict__ Qb,
    const float* __restrict__ RT, const float* __restrict__ att_w2,
    const float* __restrict__ att_b2, const float* __restrict__ vbuf,
    int l, unsigned short* __restrict__ attn_bf) {
    int bid = blockIdx.x;          // 512
    int bh = bid & 7;
    int b = bh >> 2, h = bh & 3;
    int i0 = (63 - (bid >> 3)) * 4;   // biggest tiles first
    int t = threadIdx.x;           // 0..1023
    int j = t & 255;
    int cs = t >> 8;               // c-split 0..3
    __shared__ float shQW[256][8];     // [c][q0..q3, w2, pad]
    __shared__ float part[4][4][256];  // [cs][ii][j]
    __shared__ float p_lds[4][256];    // softmax rows
    __shared__ float pvp[4][4][64];    // [strip][row][d]
    { int ii = t >> 8, c = t & 255;
      shQW[c][ii] = Qb[((b * TDIM + (i0 + ii)) * NH + h) * CDIM + c]; }
    if (t < 256) shQW[t][4] = att_w2[(l * NH + h) * CDIM + t];
    __syncthreads();
    f32x2 accA = {0.f, 0.f}, accB = {0.f, 0.f};
    int m = i0 - j;
    int mm = max(m, -3);           // clamped; garbage lanes are discarded j>i lanes
    if ((t & 192) <= i0 + 3) {     // wave-uniform skip of fully-masked j-strips
        const float* pk = PT + ((size_t)(b * NH + h) * CDIM + cs * 64) * TDIM + j;
        const float* rk = RT + ((size_t)h * CDIM + cs * 64) * TDIM + mm;
        float p_n = *pk;
        f32x4 r_n; __builtin_memcpy(&r_n, rk, 16);
        #pragma unroll 4
        for (int k = 0; k < 64; ++k) {
            float p_c = p_n; f32x4 r_c = r_n;
            pk += TDIM; rk += TDIM;
            if (k < 63) { p_n = *pk; __builtin_memcpy(&r_n, rk, 16); }  // prefetch next c
            int c = cs * 64 + k;
            f32x4 q4 = *(const f32x4*)(&shQW[c][0]);
            float w2v = shQW[c][4];
            f32x2 zA, zB;
            zA.x = p_c + q4.x + r_c.x; zA.y = p_c + q4.y + r_c.y;
            zB.x = p_c + q4.z + r_c.z; zB.y = p_c + q4.w + r_c.w;
            accA += gelu2(zA) * w2v;
            accB += gelu2(zB) * w2v;
        }
    }
    part[cs][0][j] = accA.x; part[cs][1][j] = accA.y;
    part[cs][2][j] = accB.x; part[cs][3][j] = accB.y;
    __syncthreads();
    if (t < 256) {
        #pragma unroll
        for (int ii = 0; ii < 4; ++ii) {
            float s = part[0][ii][t] + part[1][ii][t] + part[2][ii][t] + part[3][ii][t];
            part[0][ii][t] = s;
        }
    }
    __syncthreads();
    if (t < 256) {
        float b2 = att_b2[l * NH + h];
        int lane = t & 63, w = t >> 6;
        int i = i0 + w;
        float lv[4];
        #pragma unroll
        for (int s = 0; s < 4; ++s) {
            int jj = lane + s * 64;
            lv[s] = (jj <= i) ? (part[0][w][jj] + b2) * 0.0625f : -1e30f;
        }
        float mx = fmaxf(fmaxf(lv[0], lv[1]), fmaxf(lv[2], lv[3]));
        #pragma unroll
        for (int off = 32; off; off >>= 1) mx = fmaxf(mx, __shfl_xor(mx, off));
        float es[4], sum = 0.f;
        #pragma unroll
        for (int s = 0; s < 4; ++s) { es[s] = exp2f((lv[s] - mx) * 1.4426950409f); sum += es[s]; }
        #pragma unroll
        for (int off = 32; off; off >>= 1) sum += __shfl_xor(sum, off);
        float inv = 1.0f / sum;
        #pragma unroll
        for (int s = 0; s < 4; ++s) p_lds[w][lane + s * 64] = es[s] * inv;  // masked -> 0
    }
    __syncthreads();
    {   // PV: strip = t>>8, row = (t>>6)&3, d = t&63
        int strip = t >> 8, row = (t >> 6) & 3, d = t & 63;
        const float* vp = vbuf + ((size_t)(b * NH + h) * TDIM + strip * 64) * DHS + d;
        const float* pl = &p_lds[row][strip * 64];
        float acc = 0.f;
        #pragma unroll 8
        for (int jj = 0; jj < 64; ++jj)
            acc = fmaf(pl[jj], vp[(size_t)jj * DHS], acc);
        pvp[strip][row][d] = acc;
    }
    __syncthreads();
    if (t < 256) {
        int row = t >> 6, d = t & 63;
        float s = pvp[0][row][d] + pvp[1][row][d] + pvp[2][row][d] + pvp[3][row][d];
        attn_bf[((size_t)(b * TDIM + i0 + row)) * CDIM + h * DHS + d] = f2bf(s);
    }
}

// proj GEMM: pbuf[512,256] = attn_bf @ Wproj^T + proj_b. grid (8,4)=32.
__global__ __launch_bounds__(256) void k_proj_gemm(
    const unsigned short* __restrict__ attn_bf, // [512][256]
    const unsigned short* __restrict__ Wproj,   // [L][256][256]
    const float* __restrict__ proj_b,
    float* __restrict__ pbuf, int l)
{
    __shared__ unsigned short A_lds[64 * 128];
    __shared__ unsigned short B_lds[64 * 128];
    int t = threadIdx.x;
    int r0 = (blockIdx.x & 7) * 64;
    int n0 = (blockIdx.x >> 3) * 64;
    f32x4 acc[2][2] = {};
    gemm64_core(attn_bf + (size_t)r0 * 256, 256,
                Wproj + (size_t)l * 65536 + (size_t)n0 * 256, 256, 256, t, acc, A_lds, B_lds);
    int lane = t & 63, w = t >> 6;
    int wm = (w >> 1) * 32, wn = (w & 1) * 32;
    int l15 = lane & 15;
    #pragma unroll
    for (int fm = 0; fm < 2; ++fm)
    #pragma unroll
    for (int fn = 0; fn < 2; ++fn) {
        int col = n0 + wn + fn * 16 + l15;
        float bb = proj_b[l * CDIM + col];
        #pragma unroll
        for (int r = 0; r < 4; ++r) {
            int row = r0 + wm + fm * 16 + (lane >> 4) * 4 + r;
            pbuf[(size_t)row * CDIM + col] = acc[fm][fn][r] + bb;
        }
    }
}

// fused residual + LN: x += pbuf; hbuf_bf = bf16(LN(x)). 512 blocks.
__global__ void k_resln(const float* __restrict__ pbuf, float* __restrict__ x,
                        const float* __restrict__ lg, const float* __restrict__ lb,
                        unsigned short* __restrict__ hbuf_bf) {
    int bi = blockIdx.x;
    int t = threadIdx.x;           // 256
    __shared__ float red[CDIM];
    float val = x[bi * CDIM + t] + pbuf[bi * CDIM + t];
    x[bi * CDIM + t] = val;
    red[t] = val; __syncthreads();
    for (int s = 128; s > 0; s >>= 1) { if (t < s) red[t] += red[t + s]; __syncthreads(); }
    float mean = red[0] * (1.f / 256.f); __syncthreads();
    float dv = val - mean;
    red[t] = dv * dv; __syncthreads();
    for (int s = 128; s > 0; s >>= 1) { if (t < s) red[t] += red[t + s]; __syncthreads(); }
    float r = rsqrtf(red[0] * (1.f / 256.f) + 1e-5f);
    hbuf_bf[bi * CDIM + t] = f2bf(dv * r * lg[t] + lb[t]);
}

// ff1 GEMM: fbuf_bf[512,1024] = bf16(gelu(hbuf_bf @ Wff1^T)). grid (8, 16).
__global__ __launch_bounds__(256) void k_ff1_gemm(
    const unsigned short* __restrict__ hbuf_bf, // [512][256]
    const unsigned short* __restrict__ Wff1,    // [L][1024][256]
    unsigned short* __restrict__ fbuf_bf, int l)
{
    __shared__ unsigned short A_lds[64 * 128];
    __shared__ unsigned short B_lds[64 * 128];
    int t = threadIdx.x;
    int r0 = blockIdx.x * 64;
    int n0 = blockIdx.y * 64;
    const unsigned short* Bp = Wff1 + (size_t)l * 1024 * 256 + (size_t)n0 * 256;
    f32x4 acc[2][2] = {};
    gemm64_core(hbuf_bf + (size_t)r0 * 256, 256, Bp, 256, 256, t, acc, A_lds, B_lds);
    int lane = t & 63, w = t >> 6;
    int wm = (w >> 1) * 32, wn = (w & 1) * 32;
    int l15 = lane & 15;
    #pragma unroll
    for (int fm = 0; fm < 2; ++fm)
    #pragma unroll
    for (int fn = 0; fn < 2; ++fn) {
        int col = n0 + wn + fn * 16 + l15;
        #pragma unroll
        for (int r = 0; r < 4; ++r) {
            int row = r0 + wm + fm * 16 + (lane >> 4) * 4 + r;
            fbuf_bf[(size_t)row * FHID + col] = f2bf(gelu_f(acc[fm][fn][r]));
        }
    }
}

// ff2 GEMM: x += fbuf_bf @ Wff2^T + b2; writes x f32 + x_bf. grid (8, 4). K=1024.
__global__ __launch_bounds__(256) void k_ff2_gemm(
    const unsigned short* __restrict__ fbuf_bf, // [512][1024]
    const unsigned short* __restrict__ Wff2,    // [L][256][1024]
    const float* __restrict__ ff_b2,
    float* __restrict__ x, unsigned short* __restrict__ x_bf, int l)
{
    __shared__ unsigned short A_lds[64 * 128];
    __shared__ unsigned short B_lds[64 * 128];
    int t = threadIdx.x;
    int r0 = blockIdx.x * 64;
    int n0 = blockIdx.y * 64;
    const unsigned short* Bp = Wff2 + (size_t)l * 256 * 1024 + (size_t)n0 * 1024;
    f32x4 acc[2][2] = {};
    gemm64_core(fbuf_bf + (size_t)r0 * 1024, 1024, Bp, 1024, 1024, t, acc, A_lds, B_lds);
    int lane = t & 63, w = t >> 6;
    int wm = (w >> 1) * 32, wn = (w & 1) * 32;
    int l15 = lane & 15;
    #pragma unroll
    for (int fm = 0; fm < 2; ++fm)
    #pragma unroll
    for (int fn = 0; fn < 2; ++fn) {
        int col = n0 + wn + fn * 16 + l15;
        float bb = ff_b2[l * CDIM + col];
        #pragma unroll
        for (int r = 0; r < 4; ++r) {
            int row = r0 + wm + fm * 16 + (lane >> 4) * 4 + r;
            float v = x[(size_t)row * CDIM + col] + acc[fm][fn][r] + bb;
            x[(size_t)row * CDIM + col] = v;
            x_bf[(size_t)row * CDIM + col] = f2bf(v);
        }
    }
}

// final LN -> bf16
__global__ void k_lnf_bf16(const float* __restrict__ x, const float* __restrict__ g,
                           const float* __restrict__ bb, unsigned short* __restrict__ out) {
    int bi = blockIdx.x;
    int t = threadIdx.x;           // 256
    __shared__ float red[CDIM];
    float val = x[bi * CDIM + t];
    red[t] = val; __syncthreads();
    for (int s = 128; s > 0; s >>= 1) { if (t < s) red[t] += red[t + s]; __syncthreads(); }
    float mean = red[0] * (1.f / 256.f); __syncthreads();
    float dv = val - mean;
    red[t] = dv * dv; __syncthreads();
    for (int s = 128; s > 0; s >>= 1) { if (t < s) red[t] += red[t + s]; __syncthreads(); }
    float r = rsqrtf(red[0] * (1.f / 256.f) + 1e-5f);
    out[bi * CDIM + t] = f2bf(dv * r * g[t] + bb[t]);
}

// head GEMM: out[512,8000] = xf_bf @ wT^T + head_b. grid (8, 125).
__global__ __launch_bounds__(256) void k_head_mfma(
    const unsigned short* __restrict__ xf_bf,   // [512][256]
    const unsigned short* __restrict__ wT,      // [8000][256]
    const float* __restrict__ head_b,
    float* __restrict__ out)
{
    __shared__ unsigned short A_lds[64 * 128];
    __shared__ unsigned short B_lds[64 * 128];
    int t = threadIdx.x;
    int r0 = blockIdx.x * 64;
    int n0 = blockIdx.y * 64;
    f32x4 acc[2][2] = {};
    gemm64_core(xf_bf + (size_t)r0 * 256, 256, wT + (size_t)n0 * 256, 256, 256,
                t, acc, A_lds, B_lds);
    int lane = t & 63, w = t >> 6;
    int wm = (w >> 1) * 32, wn = (w & 1) * 32;
    int l15 = lane & 15;
    #pragma unroll
    for (int fm = 0; fm < 2; ++fm)
    #pragma unroll
    for (int fn = 0; fn < 2; ++fn) {
        int col = n0 + wn + fn * 16 + l15;
        float hb = head_b[col];
        #pragma unroll
        for (int r = 0; r < 4; ++r) {
            int row = r0 + wm + fm * 16 + (lane >> 4) * 4 + r;
            out[(size_t)row * NV + col] = acc[fm][fn][r] + hb;
        }
    }
}

extern "C" void kernel_launch(void* const* d_in, const int* in_sizes, int n_in,
                              void* d_out, int out_size, void* d_ws, size_t ws_size,
                              hipStream_t stream) {
    const int*   idx       = (const int*)  d_in[0];
    const float* tok_emb   = (const float*)d_in[1];
    const float* pos_table = (const float*)d_in[2];
    const float* pos_w1    = (const float*)d_in[3];
    const float* pos_w2    = (const float*)d_in[4];
    const float* pos_b2    = (const float*)d_in[5];
    const float* pos_ln_g  = (const float*)d_in[6];
    const float* pos_ln_b  = (const float*)d_in[7];
    const float* att_w1    = (const float*)d_in[8];
    const float* att_w2    = (const float*)d_in[9];
    const float* att_b2    = (const float*)d_in[10];
    const float* val_w     = (const float*)d_in[11];
    const float* proj_w    = (const float*)d_in[12];
    const float* proj_b    = (const float*)d_in[13];
    const float* ln2_g     = (const float*)d_in[14];
    const float* ln2_b     = (const float*)d_in[15];
    const float* ff_w1     = (const float*)d_in[16];
    const float* ff_w2     = (const float*)d_in[17];
    const float* ff_b2     = (const float*)d_in[18];
    const float* lnf_g     = (const float*)d_in[19];
    const float* lnf_b     = (const float*)d_in[20];
    const float* head_w    = (const float*)d_in[21];
    const float* head_b    = (const float*)d_in[22];
    float* out = (float*)d_out;

    float* ws = (float*)d_ws;
    float* x    = ws;  ws += NB * TDIM * CDIM;        // 131072
    float* PT   = ws;  ws += NB * NH * CDIM * TDIM;   // 524288
    float* Qb   = ws;  ws += NB * TDIM * NH * CDIM;   // 524288
    ws += 16;                                         // guard before RT (k_wei reads RT-3)
    float* RT   = ws;  ws += NH * CDIM * TDIM;        // 262144
    float* vbuf = ws;  ws += NB * NH * TDIM * DHS;    // 131072
    float* pbuf = PT;                                 // alias: disjoint lifetimes
    unsigned short* x_bf    = (unsigned short*)ws; ws += NB * TDIM * CDIM / 2;
    unsigned short* ped_bf  = (unsigned short*)ws; ws += TDIM * 2 * CDIM / 2;
    unsigned short* hbuf_bf = (unsigned short*)ws; ws += NB * TDIM * CDIM / 2;
    unsigned short* xf_bf   = (unsigned short*)ws; ws += NB * TDIM * CDIM / 2;
    unsigned short* attn_bf = (unsigned short*)ws; ws += NB * TDIM * CDIM / 2;
    unsigned short* fbuf_bf = (unsigned short*)ws; ws += NB * TDIM * FHID / 2;
    unsigned short* wT      = (unsigned short*)ws; ws += NV * CDIM / 2;
    unsigned short* W1r     = (unsigned short*)ws; ws += 2 * 1024 * 512 / 2;
    unsigned short* Wff1    = (unsigned short*)ws; ws += 2 * 1024 * 256 / 2;
    unsigned short* Wff2    = (unsigned short*)ws; ws += 2 * 256 * 1024 / 2;
    unsigned short* Wv      = (unsigned short*)ws; ws += 2 * NH * DHS * CDIM / 2;
    unsigned short* Wproj   = (unsigned short*)ws; ws += 2 * CDIM * CDIM / 2;
    // total ~17.5 MB

    k_tcast_all<<<4304, 256, 0, stream>>>(head_w, att_w1, ff_w1, ff_w2, val_w, proj_w,
                                          wT, W1r, Wff1, Wff2, Wv, Wproj);
    k_pre<<<512, 512, 0, stream>>>(idx, tok_emb, pos_table, pos_w1, pos_w2, pos_b2,
                                   pos_ln_g, pos_ln_b, x, x_bf, ped_bf);

    for (int l = 0; l < 2; ++l) {
        k_qkv<<<352, 256, 0, stream>>>(x_bf, ped_bf, W1r, Wv, PT, Qb, RT, vbuf, l);
        k_wei<<<NB * NH * TDIM / 4, 1024, 0, stream>>>(PT, Qb, RT, att_w2, att_b2, vbuf,
                                                       l, attn_bf);
        k_proj_gemm<<<32, 256, 0, stream>>>(attn_bf, Wproj, proj_b, pbuf, l);
        k_resln<<<NB * TDIM, 256, 0, stream>>>(pbuf, x, ln2_g + l * CDIM, ln2_b + l * CDIM, hbuf_bf);
        k_ff1_gemm<<<dim3(8, 16), 256, 0, stream>>>(hbuf_bf, Wff1, fbuf_bf, l);
        k_ff2_gemm<<<dim3(8, 4), 256, 0, stream>>>(fbuf_bf, Wff2, ff_b2, x, x_bf, l);
    }

    k_lnf_bf16<<<NB * TDIM, 256, 0, stream>>>(x, lnf_g, lnf_b, xf_bf);
    k_head_mfma<<<dim3(8, 125), 256, 0, stream>>>(xf_bf, wT, head_b, out);
}

// Round 7
// 320.381 us; speedup vs baseline: 1.0998x; 1.0998x over previous
//
#include <hip/hip_runtime.h>
#include <hip/hip_bf16.h>
#include <math.h>

// Problem dims (fixed)
constexpr int TDIM = 256;   // sequence length t
constexpr int CDIM = 256;   // channels C
constexpr int NH   = 4;     // heads
constexpr int DHS  = 64;    // head size
constexpr int FHID = 1024;  // ffn hidden
constexpr int NV   = 8000;  // vocab
constexpr int NB   = 2;     // batch

typedef __attribute__((ext_vector_type(8))) short bf16x8;
typedef __attribute__((ext_vector_type(4))) float f32x4;
typedef __attribute__((ext_vector_type(2))) float f32x2;
typedef __attribute__((ext_vector_type(4))) unsigned int uint4v;

__device__ __forceinline__ float gelu_f(float x) {
    return 0.5f * x * (1.0f + erff(x * 0.70710678118654752440f));
}

// packed tanh-form gelu on 2 lanes: x*E/(E+1), E=exp2(x*(kA+kB*x^2))
__device__ __forceinline__ f32x2 gelu2(f32x2 x) {
    constexpr float kA = 2.0f * 1.4426950408889634f * 0.7978845608028654f;
    constexpr float kB = kA * 0.044715f;
    f32x2 arg = x * (kA + kB * (x * x));
    arg.x = fminf(arg.x, 120.f);
    arg.y = fminf(arg.y, 120.f);
    float e0 = exp2f(arg.x), e1 = exp2f(arg.y);
    f32x2 num; num.x = x.x * e0; num.y = x.y * e1;
    f32x2 den; den.x = __builtin_amdgcn_rcpf(e0 + 1.f); den.y = __builtin_amdgcn_rcpf(e1 + 1.f);
    return num * den;
}

__device__ __forceinline__ unsigned short f2bf(float f) {
    unsigned int u = __float_as_uint(f);
    unsigned int r = (u + 0x7FFF + ((u >> 16) & 1)) >> 16;   // RNE
    return (unsigned short)r;
}

// ---------------- merged weight transpose+cast (all 6 tensors, one launch) ----------
__global__ __launch_bounds__(256) void k_tcast_all(
    const float* __restrict__ head_w, const float* __restrict__ att_w1,
    const float* __restrict__ ff_w1, const float* __restrict__ ff_w2,
    const float* __restrict__ val_w, const float* __restrict__ proj_w,
    unsigned short* __restrict__ wT, unsigned short* __restrict__ W1r,
    unsigned short* __restrict__ Wff1, unsigned short* __restrict__ Wff2,
    unsigned short* __restrict__ Wv, unsigned short* __restrict__ Wproj)
{
    int q = blockIdx.x;
    const float* src; unsigned short* dst; int R, C, tx, ty;
    if (q < 2000)      { src = head_w; dst = wT; R = 256; C = 8000; tx = q % 250; ty = q / 250; }
    else if (q < 3024) { int u = q - 2000, s = u >> 7, v = u & 127;
        src = att_w1 + (size_t)s * 512 * 256; dst = W1r + (size_t)s * 512 * 256;
        R = 512; C = 256; tx = v & 7; ty = v >> 3; }
    else if (q < 3536) { int u = q - 3024, s = u >> 8, v = u & 255;
        src = ff_w1 + (size_t)s * 256 * 1024; dst = Wff1 + (size_t)s * 256 * 1024;
        R = 256; C = 1024; tx = v & 31; ty = v >> 5; }
    else if (q < 4048) { int u = q - 3536, s = u >> 8, v = u & 255;
        src = ff_w2 + (size_t)s * 1024 * 256; dst = Wff2 + (size_t)s * 1024 * 256;
        R = 1024; C = 256; tx = v & 7; ty = v >> 3; }
    else if (q < 4176) { int u = q - 4048, s = u >> 4, v = u & 15;
        src = val_w + (size_t)s * 256 * 64; dst = Wv + (size_t)s * 256 * 64;
        R = 256; C = 64; tx = v & 1; ty = v >> 1; }
    else { int u = q - 4176, s = u >> 6, v = u & 63;
        src = proj_w + (size_t)s * 256 * 256; dst = Wproj + (size_t)s * 256 * 256;
        R = 256; C = 256; tx = v & 7; ty = v >> 3; }
    __shared__ float tile[32][33];
    int c0 = tx * 32, r0 = ty * 32, t = threadIdx.x;
    #pragma unroll
    for (int e = 0; e < 4; ++e) {
        int lin = e * 256 + t; int rr = lin >> 5, cc = lin & 31;
        tile[rr][cc] = src[(size_t)(r0 + rr) * C + c0 + cc];
    }
    __syncthreads();
    #pragma unroll
    for (int e = 0; e < 4; ++e) {
        int lin = e * 256 + t; int cc = lin >> 5, rr = lin & 31;
        dst[(size_t)(c0 + cc) * R + r0 + rr] = f2bf(tile[rr][cc]);
    }
}

// merged embed + pe. grid 512, block 512.
__global__ __launch_bounds__(512) void k_pre(
    const int* __restrict__ idx, const float* __restrict__ tok_emb,
    const float* __restrict__ pos_table, const float* __restrict__ pos_w1,
    const float* __restrict__ pos_w2, const float* __restrict__ pos_b2,
    const float* __restrict__ g, const float* __restrict__ bb,
    float* __restrict__ x, unsigned short* __restrict__ x_bf,
    unsigned short* __restrict__ ped_bf)
{
    int bid = blockIdx.x;
    int t = threadIdx.x;           // 512
    if (bid < 256) {
        int r = bid * 2 + (t >> 8);
        int c = t & 255;
        int tok = idx[r];
        float v = tok_emb[(size_t)tok * CDIM + c];
        x[r * CDIM + c] = v;
        x_bf[r * CDIM + c] = f2bf(v);
        return;
    }
    int d = bid - 256;
    __shared__ float xs[CDIM];
    __shared__ float hs[512];
    __shared__ float red[512];
    if (t < CDIM) xs[t] = pos_table[d * CDIM + t];
    __syncthreads();
    float acc = 0.f;
    for (int c = 0; c < CDIM; ++c) acc += xs[c] * pos_w1[(size_t)c * 512 + t];
    hs[t] = gelu_f(acc);
    __syncthreads();
    float acc2 = pos_b2[t];
    for (int z = 0; z < 512; ++z) acc2 += hs[z] * pos_w2[(size_t)z * 512 + t];
    red[t] = acc2; __syncthreads();
    for (int s = 256; s > 0; s >>= 1) { if (t < s) red[t] += red[t + s]; __syncthreads(); }
    float mean = red[0] * (1.f / 512.f); __syncthreads();
    float dv = acc2 - mean;
    red[t] = dv * dv; __syncthreads();
    for (int s = 256; s > 0; s >>= 1) { if (t < s) red[t] += red[t + s]; __syncthreads(); }
    float r = rsqrtf(red[0] * (1.f / 512.f) + 1e-5f);
    ped_bf[d * 512 + t] = f2bf(dv * r * g[t] + bb[t]);
}

// ---------------- shared bf16 MFMA 64x64-tile core, K-chunk 128 (32KB LDS) ----------
__device__ __forceinline__ void gemm64_core(
    const unsigned short* __restrict__ A, int lda,
    const unsigned short* __restrict__ B, int ldb,
    int kLen, int t, f32x4 acc[2][2],
    unsigned short* __restrict__ A_lds, unsigned short* __restrict__ B_lds)
{
    int lane = t & 63;
    int w = t >> 6;
    int wm = (w >> 1) * 32, wn = (w & 1) * 32;
    int l15 = lane & 15;
    int lk = (lane >> 4) * 8;
    for (int kc = 0; kc < kLen; kc += 128) {
        #pragma unroll
        for (int it = 0; it < 4; ++it) {
            int chunk = it * 256 + t;       // 1024 x 16B chunks
            int row = chunk >> 4;           // 16 chunks per 128-col row
            int c16 = chunk & 15;
            uint4v va = *(const uint4v*)(A + (size_t)row * lda + kc + c16 * 8);
            uint4v vb = *(const uint4v*)(B + (size_t)row * ldb + kc + c16 * 8);
            int lin = row * 256 + c16 * 16;
            int phys = lin ^ ((row & 7) << 4);
            *(uint4v*)((char*)A_lds + phys) = va;
            *(uint4v*)((char*)B_lds + phys) = vb;
        }
        __syncthreads();
        #pragma unroll
        for (int ks = 0; ks < 4; ++ks) {
            int kb = ks * 32 + lk;
            bf16x8 a[2], b[2];
            #pragma unroll
            for (int f = 0; f < 2; ++f) {
                int mrow = wm + f * 16 + l15;
                int lina = mrow * 256 + kb * 2;
                a[f] = *(const bf16x8*)((const char*)A_lds + (lina ^ ((mrow & 7) << 4)));
                int nrow = wn + f * 16 + l15;
                int linb = nrow * 256 + kb * 2;
                b[f] = *(const bf16x8*)((const char*)B_lds + (linb ^ ((nrow & 7) << 4)));
            }
            acc[0][0] = __builtin_amdgcn_mfma_f32_16x16x32_bf16(a[0], b[0], acc[0][0], 0, 0, 0);
            acc[0][1] = __builtin_amdgcn_mfma_f32_16x16x32_bf16(a[0], b[1], acc[0][1], 0, 0, 0);
            acc[1][0] = __builtin_amdgcn_mfma_f32_16x16x32_bf16(a[1], b[0], acc[1][0], 0, 0, 0);
            acc[1][1] = __builtin_amdgcn_mfma_f32_16x16x32_bf16(a[1], b[1], acc[1][1], 0, 0, 0);
        }
        __syncthreads();
    }
}

// merged QKV: bid<256 -> pq GEMM; 256..319 -> r GEMM; 320..351 -> v GEMM
__global__ __launch_bounds__(256) void k_qkv(
    const unsigned short* __restrict__ x_bf,   // [512][256]
    const unsigned short* __restrict__ ped_bf, // [256][512]
    const unsigned short* __restrict__ W1r,    // [L][1024][512]
    const unsigned short* __restrict__ Wv,     // [L*4][64][256]
    float* __restrict__ PT, float* __restrict__ Qb, float* __restrict__ RT,
    unsigned short* __restrict__ vT_bf, int l)
{
    __shared__ unsigned short A_lds[64 * 128];
    __shared__ unsigned short B_lds[64 * 128];
    int t = threadIdx.x;
    int bid = blockIdx.x;
    int lane = t & 63, w = t >> 6;
    int wm = (w >> 1) * 32, wn = (w & 1) * 32;
    int l15 = lane & 15;
    f32x4 acc[2][2] = {};
    if (bid < 256) {           // pq: out[512,2048] = x_bf @ W1
        int r0 = (bid & 7) * 64;
        int n0 = (bid >> 3) * 64;
        int h = n0 >> 9, isQ = (n0 >> 8) & 1;
        const unsigned short* Bp = W1r + (size_t)l * 1024 * 512
                                 + (size_t)(h * 256 + (n0 & 255)) * 512 + isQ * 256;
        gemm64_core(x_bf + (size_t)r0 * 256, 256, Bp, 512, 256, t, acc, A_lds, B_lds);
        #pragma unroll
        for (int fm = 0; fm < 2; ++fm)
        #pragma unroll
        for (int fn = 0; fn < 2; ++fn) {
            int col = n0 + wn + fn * 16 + l15;
            int c = col & 255;
            #pragma unroll
            for (int r = 0; r < 4; ++r) {
                int row = r0 + wm + fm * 16 + (lane >> 4) * 4 + r;
                int b = row >> 8, ij = row & 255;
                if (isQ) Qb[((b * TDIM + ij) * NH + h) * CDIM + c] = acc[fm][fn][r];
                else     PT[((size_t)(b * NH + h) * CDIM + c) * TDIM + ij] = acc[fm][fn][r];
            }
        }
    } else if (bid < 320) {    // r: out[256 d, 1024 (h,c)] = ped_bf @ W1r^T
        int u = bid - 256;
        int r0 = (u & 3) * 64;
        int n0 = (u >> 2) * 64;
        const unsigned short* Bp = W1r + (size_t)l * 1024 * 512 + (size_t)n0 * 512;
        gemm64_core(ped_bf + (size_t)r0 * 512, 512, Bp, 512, 512, t, acc, A_lds, B_lds);
        #pragma unroll
        for (int fm = 0; fm < 2; ++fm)
        #pragma unroll
        for (int fn = 0; fn < 2; ++fn) {
            int col = n0 + wn + fn * 16 + l15;
            #pragma unroll
            for (int r = 0; r < 4; ++r) {
                int d = r0 + wm + fm * 16 + (lane >> 4) * 4 + r;
                RT[(size_t)col * TDIM + d] = acc[fm][fn][r];
            }
        }
    } else {                   // v -> vT_bf[(b,h,d)][j]
        int u = bid - 320;
        int r0 = (u & 7) * 64;
        int n0 = (u >> 3) * 64;
        int h = n0 >> 6;
        const unsigned short* Bp = Wv + ((size_t)l * NH + h) * DHS * CDIM;
        gemm64_core(x_bf + (size_t)r0 * 256, 256, Bp, 256, 256, t, acc, A_lds, B_lds);
        #pragma unroll
        for (int fm = 0; fm < 2; ++fm)
        #pragma unroll
        for (int fn = 0; fn < 2; ++fn) {
            int col = n0 + wn + fn * 16 + l15;
            int d = col & 63;
            #pragma unroll
            for (int r = 0; r < 4; ++r) {
                int row = r0 + wm + fm * 16 + (lane >> 4) * 4 + r;
                int b = row >> 8, j = row & 255;
                vT_bf[(((size_t)b * NH + h) * DHS + d) * TDIM + j] = f2bf(acc[fm][fn][r]);
            }
        }
    }
}

// wei + softmax, wave-balanced: ns strips x (16/ns) c-chunks, all 16 waves always busy.
__global__ __launch_bounds__(1024, 8) void k_wei(
    const float* __restrict__ PT, const float* __restrict__ Qb,
    const float* __restrict__ RT, const float* __restrict__ att_w2,
    const float* __restrict__ att_b2, int l, unsigned short* __restrict__ wei_bf) {
    int bid = blockIdx.x;          // 512
    int bh = bid & 7;
    int b = bh >> 2, h = bh & 3;
    int i0 = (63 - (bid >> 3)) * 4;   // biggest tiles first
    int t = threadIdx.x;           // 0..1023
    int wid = t >> 6, lane = t & 63;
    // rounded live-strip count (pow2): ns in {1,2,4}
    int nlog = (i0 + 4 <= 64) ? 0 : (i0 + 4 <= 128) ? 1 : 2;
    int ns = 1 << nlog;
    int nchunks = 16 >> nlog;
    int c_len = 16 << nlog;
    int strip = wid & (ns - 1);
    int cchunk = wid >> nlog;
    int c0 = cchunk * c_len;
    int j = strip * 64 + lane;
    __shared__ float shQW[256][8];     // [c][q0..q3, w2, pad]; reused for row-sums
    __shared__ float part[16][4][64];  // [wid][row][lane]
    { int ii = t >> 8, c = t & 255;
      shQW[c][ii] = Qb[((b * TDIM + (i0 + ii)) * NH + h) * CDIM + c]; }
    if (t < 256) shQW[t][4] = att_w2[(l * NH + h) * CDIM + t];
    __syncthreads();
    f32x2 accA = {0.f, 0.f}, accB = {0.f, 0.f};
    int mm = max(i0 - j, -3);      // clamped; garbage lanes are discarded j>i lanes
    {
        const float* pk = PT + ((size_t)(b * NH + h) * CDIM + c0) * TDIM + j;
        const float* rk = RT + ((size_t)h * CDIM + c0) * TDIM + mm;
        #pragma unroll 4
        for (int k = 0; k < c_len; ++k) {
            float p = *pk;
            f32x4 r4; __builtin_memcpy(&r4, rk, 16);
            pk += TDIM; rk += TDIM;
            int c = c0 + k;
            f32x4 q4 = *(const f32x4*)(&shQW[c][0]);
            float w2v = shQW[c][4];
            f32x2 zA, zB;
            zA.x = p + q4.x + r4.x; zA.y = p + q4.y + r4.y;
            zB.x = p + q4.z + r4.z; zB.y = p + q4.w + r4.w;
            accA += gelu2(zA) * w2v;
            accB += gelu2(zB) * w2v;
        }
    }
    part[wid][0][lane] = accA.x; part[wid][1][lane] = accA.y;
    part[wid][2][lane] = accB.x; part[wid][3][lane] = accB.y;
    __syncthreads();
    if (t < 256) {                 // per-j sum over this strip's c-chunks -> shQW[j][0..3]
        int jj = t, sj = jj >> 6, l6 = jj & 63;
        float s0 = 0, s1 = 0, s2 = 0, s3 = 0;
        for (int cc = 0; cc < nchunks; ++cc) {
            int w = ((cc << nlog) + sj) & 15;   // masked j-strips read finite garbage
            s0 += part[w][0][l6]; s1 += part[w][1][l6];
            s2 += part[w][2][l6]; s3 += part[w][3][l6];
        }
        shQW[jj][0] = s0; shQW[jj][1] = s1; shQW[jj][2] = s2; shQW[jj][3] = s3;
    }
    __syncthreads();
    if (t < 256) {
        float b2 = att_b2[l * NH + h];
        int l6 = t & 63, w = t >> 6;
        int i = i0 + w;
        float lv[4];
        #pragma unroll
        for (int s = 0; s < 4; ++s) {
            int jj = l6 + s * 64;
            lv[s] = (jj <= i) ? (shQW[jj][w] + b2) * 0.0625f : -1e30f;
        }
        float mx = fmaxf(fmaxf(lv[0], lv[1]), fmaxf(lv[2], lv[3]));
        #pragma unroll
        for (int off = 32; off; off >>= 1) mx = fmaxf(mx, __shfl_xor(mx, off));
        float es[4], sum = 0.f;
        #pragma unroll
        for (int s = 0; s < 4; ++s) { es[s] = exp2f((lv[s] - mx) * 1.4426950409f); sum += es[s]; }
        #pragma unroll
        for (int off = 32; off; off >>= 1) sum += __shfl_xor(sum, off);
        float inv = 1.0f / sum;
        unsigned short* wrow = wei_bf + (((size_t)bh * TDIM) + i) * TDIM;
        #pragma unroll
        for (int s = 0; s < 4; ++s) wrow[l6 + s * 64] = f2bf(es[s] * inv);
    }
}

// av GEMM: attn_bf[(b,i)][(h,d)] = wei_bf[(b,h)] @ vT_bf[(b,h)]^T. grid 32.
__global__ __launch_bounds__(256) void k_av_gemm(
    const unsigned short* __restrict__ wei_bf,  // [8][256][256]
    const unsigned short* __restrict__ vT_bf,   // [8][64][256]
    unsigned short* __restrict__ attn_bf)       // [512][256]
{
    __shared__ unsigned short A_lds[64 * 128];
    __shared__ unsigned short B_lds[64 * 128];
    int t = threadIdx.x;
    int bid = blockIdx.x;          // 32: bh = bid>>2, m-tile = bid&3
    int bh = bid >> 2;
    int r0 = (bid & 3) * 64;
    int b = bh >> 2, h = bh & 3;
    f32x4 acc[2][2] = {};
    gemm64_core(wei_bf + (size_t)bh * 65536 + (size_t)r0 * 256, 256,
                vT_bf + (size_t)bh * 16384, 256, 256, t, acc, A_lds, B_lds);
    int lane = t & 63, w = t >> 6;
    int wm = (w >> 1) * 32, wn = (w & 1) * 32;
    int l15 = lane & 15;
    #pragma unroll
    for (int fm = 0; fm < 2; ++fm)
    #pragma unroll
    for (int fn = 0; fn < 2; ++fn) {
        int d = wn + fn * 16 + l15;    // 0..63
        #pragma unroll
        for (int r = 0; r < 4; ++r) {
            int i = r0 + wm + fm * 16 + (lane >> 4) * 4 + r;
            attn_bf[((size_t)(b * TDIM + i)) * CDIM + h * DHS + d] = f2bf(acc[fm][fn][r]);
        }
    }
}

// proj GEMM: pbuf[512,256] = attn_bf @ Wproj^T + proj_b. grid 32.
__global__ __launch_bounds__(256) void k_proj_gemm(
    const unsigned short* __restrict__ attn_bf, // [512][256]
    const unsigned short* __restrict__ Wproj,   // [L][256][256]
    const float* __restrict__ proj_b,
    float* __restrict__ pbuf, int l)
{
    __shared__ unsigned short A_lds[64 * 128];
    __shared__ unsigned short B_lds[64 * 128];
    int t = threadIdx.x;
    int r0 = (blockIdx.x & 7) * 64;
    int n0 = (blockIdx.x >> 3) * 64;
    f32x4 acc[2][2] = {};
    gemm64_core(attn_bf + (size_t)r0 * 256, 256,
                Wproj + (size_t)l * 65536 + (size_t)n0 * 256, 256, 256, t, acc, A_lds, B_lds);
    int lane = t & 63, w = t >> 6;
    int wm = (w >> 1) * 32, wn = (w & 1) * 32;
    int l15 = lane & 15;
    #pragma unroll
    for (int fm = 0; fm < 2; ++fm)
    #pragma unroll
    for (int fn = 0; fn < 2; ++fn) {
        int col = n0 + wn + fn * 16 + l15;
        float bb = proj_b[l * CDIM + col];
        #pragma unroll
        for (int r = 0; r < 4; ++r) {
            int row = r0 + wm + fm * 16 + (lane >> 4) * 4 + r;
            pbuf[(size_t)row * CDIM + col] = acc[fm][fn][r] + bb;
        }
    }
}

// fused residual + LN: x += pbuf; hbuf_bf = bf16(LN(x)). 512 blocks.
__global__ void k_resln(const float* __restrict__ pbuf, float* __restrict__ x,
                        const float* __restrict__ lg, const float* __restrict__ lb,
                        unsigned short* __restrict__ hbuf_bf) {
    int bi = blockIdx.x;
    int t = threadIdx.x;           // 256
    __shared__ float red[CDIM];
    float val = x[bi * CDIM + t] + pbuf[bi * CDIM + t];
    x[bi * CDIM + t] = val;
    red[t] = val; __syncthreads();
    for (int s = 128; s > 0; s >>= 1) { if (t < s) red[t] += red[t + s]; __syncthreads(); }
    float mean = red[0] * (1.f / 256.f); __syncthreads();
    float dv = val - mean;
    red[t] = dv * dv; __syncthreads();
    for (int s = 128; s > 0; s >>= 1) { if (t < s) red[t] += red[t + s]; __syncthreads(); }
    float r = rsqrtf(red[0] * (1.f / 256.f) + 1e-5f);
    hbuf_bf[bi * CDIM + t] = f2bf(dv * r * lg[t] + lb[t]);
}

// ff1 GEMM: fbuf_bf[512,1024] = bf16(gelu(hbuf_bf @ Wff1^T)). grid (8, 16).
__global__ __launch_bounds__(256) void k_ff1_gemm(
    const unsigned short* __restrict__ hbuf_bf, // [512][256]
    const unsigned short* __restrict__ Wff1,    // [L][1024][256]
    unsigned short* __restrict__ fbuf_bf, int l)
{
    __shared__ unsigned short A_lds[64 * 128];
    __shared__ unsigned short B_lds[64 * 128];
    int t = threadIdx.x;
    int r0 = blockIdx.x * 64;
    int n0 = blockIdx.y * 64;
    const unsigned short* Bp = Wff1 + (size_t)l * 1024 * 256 + (size_t)n0 * 256;
    f32x4 acc[2][2] = {};
    gemm64_core(hbuf_bf + (size_t)r0 * 256, 256, Bp, 256, 256, t, acc, A_lds, B_lds);
    int lane = t & 63, w = t >> 6;
    int wm = (w >> 1) * 32, wn = (w & 1) * 32;
    int l15 = lane & 15;
    #pragma unroll
    for (int fm = 0; fm < 2; ++fm)
    #pragma unroll
    for (int fn = 0; fn < 2; ++fn) {
        int col = n0 + wn + fn * 16 + l15;
        #pragma unroll
        for (int r = 0; r < 4; ++r) {
            int row = r0 + wm + fm * 16 + (lane >> 4) * 4 + r;
            fbuf_bf[(size_t)row * FHID + col] = f2bf(gelu_f(acc[fm][fn][r]));
        }
    }
}

// ff2 GEMM: x += fbuf_bf @ Wff2^T + b2; writes x f32 + x_bf. grid (8, 4). K=1024.
__global__ __launch_bounds__(256) void k_ff2_gemm(
    const unsigned short* __restrict__ fbuf_bf, // [512][1024]
    const unsigned short* __restrict__ Wff2,    // [L][256][1024]
    const float* __restrict__ ff_b2,
    float* __restrict__ x, unsigned short* __restrict__ x_bf, int l)
{
    __shared__ unsigned short A_lds[64 * 128];
    __shared__ unsigned short B_lds[64 * 128];
    int t = threadIdx.x;
    int r0 = blockIdx.x * 64;
    int n0 = blockIdx.y * 64;
    const unsigned short* Bp = Wff2 + (size_t)l * 256 * 1024 + (size_t)n0 * 1024;
    f32x4 acc[2][2] = {};
    gemm64_core(fbuf_bf + (size_t)r0 * 1024, 1024, Bp, 1024, 1024, t, acc, A_lds, B_lds);
    int lane = t & 63, w = t >> 6;
    int wm = (w >> 1) * 32, wn = (w & 1) * 32;
    int l15 = lane & 15;
    #pragma unroll
    for (int fm = 0; fm < 2; ++fm)
    #pragma unroll
    for (int fn = 0; fn < 2; ++fn) {
        int col = n0 + wn + fn * 16 + l15;
        float bb = ff_b2[l * CDIM + col];
        #pragma unroll
        for (int r = 0; r < 4; ++r) {
            int row = r0 + wm + fm * 16 + (lane >> 4) * 4 + r;
            float v = x[(size_t)row * CDIM + col] + acc[fm][fn][r] + bb;
            x[(size_t)row * CDIM + col] = v;
            x_bf[(size_t)row * CDIM + col] = f2bf(v);
        }
    }
}

// final LN -> bf16
__global__ void k_lnf_bf16(const float* __restrict__ x, const float* __restrict__ g,
                           const float* __restrict__ bb, unsigned short* __restrict__ out) {
    int bi = blockIdx.x;
    int t = threadIdx.x;           // 256
    __shared__ float red[CDIM];
    float val = x[bi * CDIM + t];
    red[t] = val; __syncthreads();
    for (int s = 128; s > 0; s >>= 1) { if (t < s) red[t] += red[t + s]; __syncthreads(); }
    float mean = red[0] * (1.f / 256.f); __syncthreads();
    float dv = val - mean;
    red[t] = dv * dv; __syncthreads();
    for (int s = 128; s > 0; s >>= 1) { if (t < s) red[t] += red[t + s]; __syncthreads(); }
    float r = rsqrtf(red[0] * (1.f / 256.f) + 1e-5f);
    out[bi * CDIM + t] = f2bf(dv * r * g[t] + bb[t]);
}

// head GEMM: out[512,8000] = xf_bf @ wT^T + head_b. grid (8, 125).
__global__ __launch_bounds__(256) void k_head_mfma(
    const unsigned short* __restrict__ xf_bf,   // [512][256]
    const unsigned short* __restrict__ wT,      // [8000][256]
    const float* __restrict__ head_b,
    float* __restrict__ out)
{
    __shared__ unsigned short A_lds[64 * 128];
    __shared__ unsigned short B_lds[64 * 128];
    int t = threadIdx.x;
    int r0 = blockIdx.x * 64;
    int n0 = blockIdx.y * 64;
    f32x4 acc[2][2] = {};
    gemm64_core(xf_bf + (size_t)r0 * 256, 256, wT + (size_t)n0 * 256, 256, 256,
                t, acc, A_lds, B_lds);
    int lane = t & 63, w = t >> 6;
    int wm = (w >> 1) * 32, wn = (w & 1) * 32;
    int l15 = lane & 15;
    #pragma unroll
    for (int fm = 0; fm < 2; ++fm)
    #pragma unroll
    for (int fn = 0; fn < 2; ++fn) {
        int col = n0 + wn + fn * 16 + l15;
        float hb = head_b[col];
        #pragma unroll
        for (int r = 0; r < 4; ++r) {
            int row = r0 + wm + fm * 16 + (lane >> 4) * 4 + r;
            out[(size_t)row * NV + col] = acc[fm][fn][r] + hb;
        }
    }
}

extern "C" void kernel_launch(void* const* d_in, const int* in_sizes, int n_in,
                              void* d_out, int out_size, void* d_ws, size_t ws_size,
                              hipStream_t stream) {
    const int*   idx       = (const int*)  d_in[0];
    const float* tok_emb   = (const float*)d_in[1];
    const float* pos_table = (const float*)d_in[2];
    const float* pos_w1    = (const float*)d_in[3];
    const float* pos_w2    = (const float*)d_in[4];
    const float* pos_b2    = (const float*)d_in[5];
    const float* pos_ln_g  = (const float*)d_in[6];
    const float* pos_ln_b  = (const float*)d_in[7];
    const float* att_w1    = (const float*)d_in[8];
    const float* att_w2    = (const float*)d_in[9];
    const float* att_b2    = (const float*)d_in[10];
    const float* val_w     = (const float*)d_in[11];
    const float* proj_w    = (const float*)d_in[12];
    const float* proj_b    = (const float*)d_in[13];
    const float* ln2_g     = (const float*)d_in[14];
    const float* ln2_b     = (const float*)d_in[15];
    const float* ff_w1     = (const float*)d_in[16];
    const float* ff_w2     = (const float*)d_in[17];
    const float* ff_b2     = (const float*)d_in[18];
    const float* lnf_g     = (const float*)d_in[19];
    const float* lnf_b     = (const float*)d_in[20];
    const float* head_w    = (const float*)d_in[21];
    const float* head_b    = (const float*)d_in[22];
    float* out = (float*)d_out;

    float* ws = (float*)d_ws;
    float* x    = ws;  ws += NB * TDIM * CDIM;        // 131072
    float* PT   = ws;  ws += NB * NH * CDIM * TDIM;   // 524288
    float* Qb   = ws;  ws += NB * TDIM * NH * CDIM;   // 524288
    ws += 16;                                         // guard before RT (k_wei reads RT-3)
    float* RT   = ws;  ws += NH * CDIM * TDIM;        // 262144
    float* pbuf = PT;                                 // alias: disjoint lifetimes
    unsigned short* x_bf    = (unsigned short*)ws; ws += NB * TDIM * CDIM / 2;
    unsigned short* ped_bf  = (unsigned short*)ws; ws += TDIM * 2 * CDIM / 2;
    unsigned short* hbuf_bf = (unsigned short*)ws; ws += NB * TDIM * CDIM / 2;
    unsigned short* xf_bf   = (unsigned short*)ws; ws += NB * TDIM * CDIM / 2;
    unsigned short* wei_bf  = (unsigned short*)ws; ws += NB * NH * TDIM * TDIM / 2;
    unsigned short* vT_bf   = (unsigned short*)ws; ws += NB * NH * DHS * TDIM / 2;
    unsigned short* attn_bf = (unsigned short*)ws; ws += NB * TDIM * CDIM / 2;
    unsigned short* wT      = (unsigned short*)ws; ws += NV * CDIM / 2;
    unsigned short* W1r     = (unsigned short*)ws; ws += 2 * 1024 * 512 / 2;
    unsigned short* Wff1    = (unsigned short*)ws; ws += 2 * 1024 * 256 / 2;
    unsigned short* Wff2    = (unsigned short*)ws; ws += 2 * 256 * 1024 / 2;
    unsigned short* Wv      = (unsigned short*)ws; ws += 2 * NH * DHS * CDIM / 2;
    unsigned short* Wproj   = (unsigned short*)ws; ws += 2 * CDIM * CDIM / 2;
    unsigned short* fbuf_bf = wei_bf;                 // alias: disjoint lifetimes

    k_tcast_all<<<4304, 256, 0, stream>>>(head_w, att_w1, ff_w1, ff_w2, val_w, proj_w,
                                          wT, W1r, Wff1, Wff2, Wv, Wproj);
    k_pre<<<512, 512, 0, stream>>>(idx, tok_emb, pos_table, pos_w1, pos_w2, pos_b2,
                                   pos_ln_g, pos_ln_b, x, x_bf, ped_bf);

    for (int l = 0; l < 2; ++l) {
        k_qkv<<<352, 256, 0, stream>>>(x_bf, ped_bf, W1r, Wv, PT, Qb, RT, vT_bf, l);
        k_wei<<<NB * NH * TDIM / 4, 1024, 0, stream>>>(PT, Qb, RT, att_w2, att_b2, l, wei_bf);
        k_av_gemm<<<32, 256, 0, stream>>>(wei_bf, vT_bf, attn_bf);
        k_proj_gemm<<<32, 256, 0, stream>>>(attn_bf, Wproj, proj_b, pbuf, l);
        k_resln<<<NB * TDIM, 256, 0, stream>>>(pbuf, x, ln2_g + l * CDIM, ln2_b + l * CDIM, hbuf_bf);
        k_ff1_gemm<<<dim3(8, 16), 256, 0, stream>>>(hbuf_bf, Wff1, fbuf_bf, l);
        k_ff2_gemm<<<dim3(8, 4), 256, 0, stream>>>(fbuf_bf, Wff2, ff_b2, x, x_bf, l);
    }

    k_lnf_bf16<<<NB * TDIM, 256, 0, stream>>>(x, lnf_g, lnf_b, xf_bf);
    k_head_mfma<<<dim3(8, 125), 256, 0, stream>>>(xf_bf, wT, head_b, out);
}

// Round 8
// 282.742 us; speedup vs baseline: 1.2462x; 1.1331x over previous
//
#include <hip/hip_runtime.h>
#include <hip/hip_bf16.h>
#include <math.h>

// Problem dims (fixed)
constexpr int TDIM = 256;   // sequence length t
constexpr int CDIM = 256;   // channels C
constexpr int NH   = 4;     // heads
constexpr int DHS  = 64;    // head size
constexpr int FHID = 1024;  // ffn hidden
constexpr int NV   = 8000;  // vocab
constexpr int NB   = 2;     // batch

typedef __attribute__((ext_vector_type(8))) short bf16x8;
typedef __attribute__((ext_vector_type(4))) float f32x4;
typedef __attribute__((ext_vector_type(2))) float f32x2;
typedef __attribute__((ext_vector_type(4))) unsigned int uint4v;

__device__ __forceinline__ float gelu_f(float x) {
    return 0.5f * x * (1.0f + erff(x * 0.70710678118654752440f));
}

// Polynomial gelu (k_wei only): erf(x/sqrt2) ~ xc*(A + B u + C u^2 + D u^3), u=xc^2,
// xc = clamp(x, +-3.4) (v_med3). Interpolates exact erf at x=1,2,3,3.4; max gelu err ~0.013.
// All full-rate VALU, no transcendentals.
__device__ __forceinline__ f32x2 gelu2p(f32x2 x) {
    constexpr float A = 0.7814073f, B = -0.1075621f, C = 0.00904825f, D = -0.000293447f;
    f32x2 xc;
    xc.x = fminf(fmaxf(x.x, -3.4f), 3.4f);
    xc.y = fminf(fmaxf(x.y, -3.4f), 3.4f);
    f32x2 u = xc * xc;
    f32x2 h = u * D + C;
    h = h * u + B;
    h = h * u + A;
    f32x2 g = xc * h;
    f32x2 t = x * 0.5f;
    return t * g + t;        // 0.5x(1+g)
}

__device__ __forceinline__ unsigned short f2bf(float f) {
    unsigned int u = __float_as_uint(f);
    unsigned int r = (u + 0x7FFF + ((u >> 16) & 1)) >> 16;   // RNE
    return (unsigned short)r;
}

// ---------------- merged weight transpose+cast (all 6 tensors, one launch) ----------
__global__ __launch_bounds__(256) void k_tcast_all(
    const float* __restrict__ head_w, const float* __restrict__ att_w1,
    const float* __restrict__ ff_w1, const float* __restrict__ ff_w2,
    const float* __restrict__ val_w, const float* __restrict__ proj_w,
    unsigned short* __restrict__ wT, unsigned short* __restrict__ W1r,
    unsigned short* __restrict__ Wff1, unsigned short* __restrict__ Wff2,
    unsigned short* __restrict__ Wv, unsigned short* __restrict__ Wproj)
{
    int q = blockIdx.x;
    const float* src; unsigned short* dst; int R, C, tx, ty;
    if (q < 2000)      { src = head_w; dst = wT; R = 256; C = 8000; tx = q % 250; ty = q / 250; }
    else if (q < 3024) { int u = q - 2000, s = u >> 7, v = u & 127;
        src = att_w1 + (size_t)s * 512 * 256; dst = W1r + (size_t)s * 512 * 256;
        R = 512; C = 256; tx = v & 7; ty = v >> 3; }
    else if (q < 3536) { int u = q - 3024, s = u >> 8, v = u & 255;
        src = ff_w1 + (size_t)s * 256 * 1024; dst = Wff1 + (size_t)s * 256 * 1024;
        R = 256; C = 1024; tx = v & 31; ty = v >> 5; }
    else if (q < 4048) { int u = q - 3536, s = u >> 8, v = u & 255;
        src = ff_w2 + (size_t)s * 1024 * 256; dst = Wff2 + (size_t)s * 1024 * 256;
        R = 1024; C = 256; tx = v & 7; ty = v >> 3; }
    else if (q < 4176) { int u = q - 4048, s = u >> 4, v = u & 15;
        src = val_w + (size_t)s * 256 * 64; dst = Wv + (size_t)s * 256 * 64;
        R = 256; C = 64; tx = v & 1; ty = v >> 1; }
    else { int u = q - 4176, s = u >> 6, v = u & 63;
        src = proj_w + (size_t)s * 256 * 256; dst = Wproj + (size_t)s * 256 * 256;
        R = 256; C = 256; tx = v & 7; ty = v >> 3; }
    __shared__ float tile[32][33];
    int c0 = tx * 32, r0 = ty * 32, t = threadIdx.x;
    #pragma unroll
    for (int e = 0; e < 4; ++e) {
        int lin = e * 256 + t; int rr = lin >> 5, cc = lin & 31;
        tile[rr][cc] = src[(size_t)(r0 + rr) * C + c0 + cc];
    }
    __syncthreads();
    #pragma unroll
    for (int e = 0; e < 4; ++e) {
        int lin = e * 256 + t; int cc = lin >> 5, rr = lin & 31;
        dst[(size_t)(c0 + cc) * R + r0 + rr] = f2bf(tile[rr][cc]);
    }
}

// merged embed + pe. grid 512, block 512.
__global__ __launch_bounds__(512) void k_pre(
    const int* __restrict__ idx, const float* __restrict__ tok_emb,
    const float* __restrict__ pos_table, const float* __restrict__ pos_w1,
    const float* __restrict__ pos_w2, const float* __restrict__ pos_b2,
    const float* __restrict__ g, const float* __restrict__ bb,
    float* __restrict__ x, unsigned short* __restrict__ x_bf,
    unsigned short* __restrict__ ped_bf)
{
    int bid = blockIdx.x;
    int t = threadIdx.x;           // 512
    if (bid < 256) {
        int r = bid * 2 + (t >> 8);
        int c = t & 255;
        int tok = idx[r];
        float v = tok_emb[(size_t)tok * CDIM + c];
        x[r * CDIM + c] = v;
        x_bf[r * CDIM + c] = f2bf(v);
        return;
    }
    int d = bid - 256;
    __shared__ float xs[CDIM];
    __shared__ float hs[512];
    __shared__ float red[512];
    if (t < CDIM) xs[t] = pos_table[d * CDIM + t];
    __syncthreads();
    float acc = 0.f;
    for (int c = 0; c < CDIM; ++c) acc += xs[c] * pos_w1[(size_t)c * 512 + t];
    hs[t] = gelu_f(acc);
    __syncthreads();
    float acc2 = pos_b2[t];
    for (int z = 0; z < 512; ++z) acc2 += hs[z] * pos_w2[(size_t)z * 512 + t];
    red[t] = acc2; __syncthreads();
    for (int s = 256; s > 0; s >>= 1) { if (t < s) red[t] += red[t + s]; __syncthreads(); }
    float mean = red[0] * (1.f / 512.f); __syncthreads();
    float dv = acc2 - mean;
    red[t] = dv * dv; __syncthreads();
    for (int s = 256; s > 0; s >>= 1) { if (t < s) red[t] += red[t + s]; __syncthreads(); }
    float r = rsqrtf(red[0] * (1.f / 512.f) + 1e-5f);
    ped_bf[d * 512 + t] = f2bf(dv * r * g[t] + bb[t]);
}

// ---------------- shared bf16 MFMA 64x64-tile core, K-chunk 128 (32KB LDS) ----------
__device__ __forceinline__ void gemm64_core(
    const unsigned short* __restrict__ A, int lda,
    const unsigned short* __restrict__ B, int ldb,
    int kLen, int t, f32x4 acc[2][2],
    unsigned short* __restrict__ A_lds, unsigned short* __restrict__ B_lds)
{
    int lane = t & 63;
    int w = t >> 6;
    int wm = (w >> 1) * 32, wn = (w & 1) * 32;
    int l15 = lane & 15;
    int lk = (lane >> 4) * 8;
    for (int kc = 0; kc < kLen; kc += 128) {
        #pragma unroll
        for (int it = 0; it < 4; ++it) {
            int chunk = it * 256 + t;       // 1024 x 16B chunks
            int row = chunk >> 4;           // 16 chunks per 128-col row
            int c16 = chunk & 15;
            uint4v va = *(const uint4v*)(A + (size_t)row * lda + kc + c16 * 8);
            uint4v vb = *(const uint4v*)(B + (size_t)row * ldb + kc + c16 * 8);
            int lin = row * 256 + c16 * 16;
            int phys = lin ^ ((row & 7) << 4);
            *(uint4v*)((char*)A_lds + phys) = va;
            *(uint4v*)((char*)B_lds + phys) = vb;
        }
        __syncthreads();
        #pragma unroll
        for (int ks = 0; ks < 4; ++ks) {
            int kb = ks * 32 + lk;
            bf16x8 a[2], b[2];
            #pragma unroll
            for (int f = 0; f < 2; ++f) {
                int mrow = wm + f * 16 + l15;
                int lina = mrow * 256 + kb * 2;
                a[f] = *(const bf16x8*)((const char*)A_lds + (lina ^ ((mrow & 7) << 4)));
                int nrow = wn + f * 16 + l15;
                int linb = nrow * 256 + kb * 2;
                b[f] = *(const bf16x8*)((const char*)B_lds + (linb ^ ((nrow & 7) << 4)));
            }
            acc[0][0] = __builtin_amdgcn_mfma_f32_16x16x32_bf16(a[0], b[0], acc[0][0], 0, 0, 0);
            acc[0][1] = __builtin_amdgcn_mfma_f32_16x16x32_bf16(a[0], b[1], acc[0][1], 0, 0, 0);
            acc[1][0] = __builtin_amdgcn_mfma_f32_16x16x32_bf16(a[1], b[0], acc[1][0], 0, 0, 0);
            acc[1][1] = __builtin_amdgcn_mfma_f32_16x16x32_bf16(a[1], b[1], acc[1][1], 0, 0, 0);
        }
        __syncthreads();
    }
}

// merged QKV: bid<256 -> pq GEMM; 256..319 -> r GEMM; 320..351 -> v GEMM
__global__ __launch_bounds__(256) void k_qkv(
    const unsigned short* __restrict__ x_bf,   // [512][256]
    const unsigned short* __restrict__ ped_bf, // [256][512]
    const unsigned short* __restrict__ W1r,    // [L][1024][512]
    const unsigned short* __restrict__ Wv,     // [L*4][64][256]
    float* __restrict__ PT, float* __restrict__ Qb, float* __restrict__ RT,
    unsigned short* __restrict__ vT_bf, int l)
{
    __shared__ unsigned short A_lds[64 * 128];
    __shared__ unsigned short B_lds[64 * 128];
    int t = threadIdx.x;
    int bid = blockIdx.x;
    int lane = t & 63, w = t >> 6;
    int wm = (w >> 1) * 32, wn = (w & 1) * 32;
    int l15 = lane & 15;
    f32x4 acc[2][2] = {};
    if (bid < 256) {           // pq: out[512,2048] = x_bf @ W1
        int r0 = (bid & 7) * 64;
        int n0 = (bid >> 3) * 64;
        int h = n0 >> 9, isQ = (n0 >> 8) & 1;
        const unsigned short* Bp = W1r + (size_t)l * 1024 * 512
                                 + (size_t)(h * 256 + (n0 & 255)) * 512 + isQ * 256;
        gemm64_core(x_bf + (size_t)r0 * 256, 256, Bp, 512, 256, t, acc, A_lds, B_lds);
        #pragma unroll
        for (int fm = 0; fm < 2; ++fm)
        #pragma unroll
        for (int fn = 0; fn < 2; ++fn) {
            int col = n0 + wn + fn * 16 + l15;
            int c = col & 255;
            #pragma unroll
            for (int r = 0; r < 4; ++r) {
                int row = r0 + wm + fm * 16 + (lane >> 4) * 4 + r;
                int b = row >> 8, ij = row & 255;
                if (isQ) Qb[((b * TDIM + ij) * NH + h) * CDIM + c] = acc[fm][fn][r];
                else     PT[((size_t)(b * NH + h) * CDIM + c) * TDIM + ij] = acc[fm][fn][r];
            }
        }
    } else if (bid < 320) {    // r: out[256 d, 1024 (h,c)] = ped_bf @ W1r^T
        int u = bid - 256;
        int r0 = (u & 3) * 64;
        int n0 = (u >> 2) * 64;
        const unsigned short* Bp = W1r + (size_t)l * 1024 * 512 + (size_t)n0 * 512;
        gemm64_core(ped_bf + (size_t)r0 * 512, 512, Bp, 512, 512, t, acc, A_lds, B_lds);
        #pragma unroll
        for (int fm = 0; fm < 2; ++fm)
        #pragma unroll
        for (int fn = 0; fn < 2; ++fn) {
            int col = n0 + wn + fn * 16 + l15;
            #pragma unroll
            for (int r = 0; r < 4; ++r) {
                int d = r0 + wm + fm * 16 + (lane >> 4) * 4 + r;
                RT[(size_t)col * TDIM + d] = acc[fm][fn][r];
            }
        }
    } else {                   // v -> vT_bf[(b,h,d)][j]
        int u = bid - 320;
        int r0 = (u & 7) * 64;
        int n0 = (u >> 3) * 64;
        int h = n0 >> 6;
        const unsigned short* Bp = Wv + ((size_t)l * NH + h) * DHS * CDIM;
        gemm64_core(x_bf + (size_t)r0 * 256, 256, Bp, 256, 256, t, acc, A_lds, B_lds);
        #pragma unroll
        for (int fm = 0; fm < 2; ++fm)
        #pragma unroll
        for (int fn = 0; fn < 2; ++fn) {
            int col = n0 + wn + fn * 16 + l15;
            int d = col & 63;
            #pragma unroll
            for (int r = 0; r < 4; ++r) {
                int row = r0 + wm + fm * 16 + (lane >> 4) * 4 + r;
                int b = row >> 8, j = row & 255;
                vT_bf[(((size_t)b * NH + h) * DHS + d) * TDIM + j] = f2bf(acc[fm][fn][r]);
            }
        }
    }
}

// wei + softmax, wave-balanced: ns strips x (16/ns) c-chunks, all 16 waves always busy.
__global__ __launch_bounds__(1024, 8) void k_wei(
    const float* __restrict__ PT, const float* __restrict__ Qb,
    const float* __restrict__ RT, const float* __restrict__ att_w2,
    const float* __restrict__ att_b2, int l, unsigned short* __restrict__ wei_bf) {
    int bid = blockIdx.x;          // 512
    int bh = bid & 7;
    int b = bh >> 2, h = bh & 3;
    int i0 = (63 - (bid >> 3)) * 4;   // biggest tiles first
    int t = threadIdx.x;           // 0..1023
    int wid = t >> 6, lane = t & 63;
    // rounded live-strip count (pow2): ns in {1,2,4}
    int nlog = (i0 + 4 <= 64) ? 0 : (i0 + 4 <= 128) ? 1 : 2;
    int ns = 1 << nlog;
    int nchunks = 16 >> nlog;
    int c_len = 16 << nlog;
    int strip = wid & (ns - 1);
    int cchunk = wid >> nlog;
    int c0 = cchunk * c_len;
    int j = strip * 64 + lane;
    __shared__ float shQW[256][8];     // [c][q0..q3, w2, pad]; reused for row-sums
    __shared__ float part[16][4][64];  // [wid][row][lane]
    { int ii = t >> 8, c = t & 255;
      shQW[c][ii] = Qb[((b * TDIM + (i0 + ii)) * NH + h) * CDIM + c]; }
    if (t < 256) shQW[t][4] = att_w2[(l * NH + h) * CDIM + t];
    __syncthreads();
    f32x2 accA = {0.f, 0.f}, accB = {0.f, 0.f};
    int mm = max(i0 - j, -3);      // clamped; garbage lanes are discarded j>i lanes
    {
        const float* pk = PT + ((size_t)(b * NH + h) * CDIM + c0) * TDIM + j;
        const float* rk = RT + ((size_t)h * CDIM + c0) * TDIM + mm;
        #pragma unroll 4
        for (int k = 0; k < c_len; ++k) {
            float p = *pk;
            f32x4 r4; __builtin_memcpy(&r4, rk, 16);
            pk += TDIM; rk += TDIM;
            int c = c0 + k;
            f32x4 q4 = *(const f32x4*)(&shQW[c][0]);
            float w2v = shQW[c][4];
            f32x2 zA, zB;
            zA.x = p + q4.x + r4.x; zA.y = p + q4.y + r4.y;
            zB.x = p + q4.z + r4.z; zB.y = p + q4.w + r4.w;
            accA += gelu2p(zA) * w2v;
            accB += gelu2p(zB) * w2v;
        }
    }
    part[wid][0][lane] = accA.x; part[wid][1][lane] = accA.y;
    part[wid][2][lane] = accB.x; part[wid][3][lane] = accB.y;
    __syncthreads();
    if (t < 256) {                 // per-j sum over this strip's c-chunks -> shQW[j][0..3]
        int jj = t, sj = jj >> 6, l6 = jj & 63;
        float s0 = 0, s1 = 0, s2 = 0, s3 = 0;
        for (int cc = 0; cc < nchunks; ++cc) {
            int w = ((cc << nlog) + sj) & 15;   // masked j-strips read finite garbage
            s0 += part[w][0][l6]; s1 += part[w][1][l6];
            s2 += part[w][2][l6]; s3 += part[w][3][l6];
        }
        shQW[jj][0] = s0; shQW[jj][1] = s1; shQW[jj][2] = s2; shQW[jj][3] = s3;
    }
    __syncthreads();
    if (t < 256) {
        float b2 = att_b2[l * NH + h];
        int l6 = t & 63, w = t >> 6;
        int i = i0 + w;
        float lv[4];
        #pragma unroll
        for (int s = 0; s < 4; ++s) {
            int jj = l6 + s * 64;
            lv[s] = (jj <= i) ? (shQW[jj][w] + b2) * 0.0625f : -1e30f;
        }
        float mx = fmaxf(fmaxf(lv[0], lv[1]), fmaxf(lv[2], lv[3]));
        #pragma unroll
        for (int off = 32; off; off >>= 1) mx = fmaxf(mx, __shfl_xor(mx, off));
        float es[4], sum = 0.f;
        #pragma unroll
        for (int s = 0; s < 4; ++s) { es[s] = exp2f((lv[s] - mx) * 1.4426950409f); sum += es[s]; }
        #pragma unroll
        for (int off = 32; off; off >>= 1) sum += __shfl_xor(sum, off);
        float inv = 1.0f / sum;
        unsigned short* wrow = wei_bf + (((size_t)bh * TDIM) + i) * TDIM;
        #pragma unroll
        for (int s = 0; s < 4; ++s) wrow[l6 + s * 64] = f2bf(es[s] * inv);
    }
}

// av GEMM: attn_bf[(b,i)][(h,d)] = wei_bf[(b,h)] @ vT_bf[(b,h)]^T. grid 32.
__global__ __launch_bounds__(256) void k_av_gemm(
    const unsigned short* __restrict__ wei_bf,  // [8][256][256]
    const unsigned short* __restrict__ vT_bf,   // [8][64][256]
    unsigned short* __restrict__ attn_bf)       // [512][256]
{
    __shared__ unsigned short A_lds[64 * 128];
    __shared__ unsigned short B_lds[64 * 128];
    int t = threadIdx.x;
    int bid = blockIdx.x;          // 32: bh = bid>>2, m-tile = bid&3
    int bh = bid >> 2;
    int r0 = (bid & 3) * 64;
    int b = bh >> 2, h = bh & 3;
    f32x4 acc[2][2] = {};
    gemm64_core(wei_bf + (size_t)bh * 65536 + (size_t)r0 * 256, 256,
                vT_bf + (size_t)bh * 16384, 256, 256, t, acc, A_lds, B_lds);
    int lane = t & 63, w = t >> 6;
    int wm = (w >> 1) * 32, wn = (w & 1) * 32;
    int l15 = lane & 15;
    #pragma unroll
    for (int fm = 0; fm < 2; ++fm)
    #pragma unroll
    for (int fn = 0; fn < 2; ++fn) {
        int d = wn + fn * 16 + l15;    // 0..63
        #pragma unroll
        for (int r = 0; r < 4; ++r) {
            int i = r0 + wm + fm * 16 + (lane >> 4) * 4 + r;
            attn_bf[((size_t)(b * TDIM + i)) * CDIM + h * DHS + d] = f2bf(acc[fm][fn][r]);
        }
    }
}

// proj GEMM: pbuf[512,256] = attn_bf @ Wproj^T + proj_b. grid 32.
__global__ __launch_bounds__(256) void k_proj_gemm(
    const unsigned short* __restrict__ attn_bf, // [512][256]
    const unsigned short* __restrict__ Wproj,   // [L][256][256]
    const float* __restrict__ proj_b,
    float* __restrict__ pbuf, int l)
{
    __shared__ unsigned short A_lds[64 * 128];
    __shared__ unsigned short B_lds[64 * 128];
    int t = threadIdx.x;
    int r0 = (blockIdx.x & 7) * 64;
    int n0 = (blockIdx.x >> 3) * 64;
    f32x4 acc[2][2] = {};
    gemm64_core(attn_bf + (size_t)r0 * 256, 256,
                Wproj + (size_t)l * 65536 + (size_t)n0 * 256, 256, 256, t, acc, A_lds, B_lds);
    int lane = t & 63, w = t >> 6;
    int wm = (w >> 1) * 32, wn = (w & 1) * 32;
    int l15 = lane & 15;
    #pragma unroll
    for (int fm = 0; fm < 2; ++fm)
    #pragma unroll
    for (int fn = 0; fn < 2; ++fn) {
        int col = n0 + wn + fn * 16 + l15;
        float bb = proj_b[l * CDIM + col];
        #pragma unroll
        for (int r = 0; r < 4; ++r) {
            int row = r0 + wm + fm * 16 + (lane >> 4) * 4 + r;
            pbuf[(size_t)row * CDIM + col] = acc[fm][fn][r] + bb;
        }
    }
}

// fused residual + LN: x += pbuf; hbuf_bf = bf16(LN(x)). 512 blocks.
__global__ void k_resln(const float* __restrict__ pbuf, float* __restrict__ x,
                        const float* __restrict__ lg, const float* __restrict__ lb,
                        unsigned short* __restrict__ hbuf_bf) {
    int bi = blockIdx.x;
    int t = threadIdx.x;           // 256
    __shared__ float red[CDIM];
    float val = x[bi * CDIM + t] + pbuf[bi * CDIM + t];
    x[bi * CDIM + t] = val;
    red[t] = val; __syncthreads();
    for (int s = 128; s > 0; s >>= 1) { if (t < s) red[t] += red[t + s]; __syncthreads(); }
    float mean = red[0] * (1.f / 256.f); __syncthreads();
    float dv = val - mean;
    red[t] = dv * dv; __syncthreads();
    for (int s = 128; s > 0; s >>= 1) { if (t < s) red[t] += red[t + s]; __syncthreads(); }
    float r = rsqrtf(red[0] * (1.f / 256.f) + 1e-5f);
    hbuf_bf[bi * CDIM + t] = f2bf(dv * r * lg[t] + lb[t]);
}

// ff1 GEMM: fbuf_bf[512,1024] = bf16(gelu(hbuf_bf @ Wff1^T)). grid (8, 16).
__global__ __launch_bounds__(256) void k_ff1_gemm(
    const unsigned short* __restrict__ hbuf_bf, // [512][256]
    const unsigned short* __restrict__ Wff1,    // [L][1024][256]
    unsigned short* __restrict__ fbuf_bf, int l)
{
    __shared__ unsigned short A_lds[64 * 128];
    __shared__ unsigned short B_lds[64 * 128];
    int t = threadIdx.x;
    int r0 = blockIdx.x * 64;
    int n0 = blockIdx.y * 64;
    const unsigned short* Bp = Wff1 + (size_t)l * 1024 * 256 + (size_t)n0 * 256;
    f32x4 acc[2][2] = {};
    gemm64_core(hbuf_bf + (size_t)r0 * 256, 256, Bp, 256, 256, t, acc, A_lds, B_lds);
    int lane = t & 63, w = t >> 6;
    int wm = (w >> 1) * 32, wn = (w & 1) * 32;
    int l15 = lane & 15;
    #pragma unroll
    for (int fm = 0; fm < 2; ++fm)
    #pragma unroll
    for (int fn = 0; fn < 2; ++fn) {
        int col = n0 + wn + fn * 16 + l15;
        #pragma unroll
        for (int r = 0; r < 4; ++r) {
            int row = r0 + wm + fm * 16 + (lane >> 4) * 4 + r;
            fbuf_bf[(size_t)row * FHID + col] = f2bf(gelu_f(acc[fm][fn][r]));
        }
    }
}

// ff2 GEMM: x += fbuf_bf @ Wff2^T + b2; writes x f32 + x_bf. grid (8, 4). K=1024.
__global__ __launch_bounds__(256) void k_ff2_gemm(
    const unsigned short* __restrict__ fbuf_bf, // [512][1024]
    const unsigned short* __restrict__ Wff2,    // [L][256][1024]
    const float* __restrict__ ff_b2,
    float* __restrict__ x, unsigned short* __restrict__ x_bf, int l)
{
    __shared__ unsigned short A_lds[64 * 128];
    __shared__ unsigned short B_lds[64 * 128];
    int t = threadIdx.x;
    int r0 = blockIdx.x * 64;
    int n0 = blockIdx.y * 64;
    const unsigned short* Bp = Wff2 + (size_t)l * 256 * 1024 + (size_t)n0 * 1024;
    f32x4 acc[2][2] = {};
    gemm64_core(fbuf_bf + (size_t)r0 * 1024, 1024, Bp, 1024, 1024, t, acc, A_lds, B_lds);
    int lane = t & 63, w = t >> 6;
    int wm = (w >> 1) * 32, wn = (w & 1) * 32;
    int l15 = lane & 15;
    #pragma unroll
    for (int fm = 0; fm < 2; ++fm)
    #pragma unroll
    for (int fn = 0; fn < 2; ++fn) {
        int col = n0 + wn + fn * 16 + l15;
        float bb = ff_b2[l * CDIM + col];
        #pragma unroll
        for (int r = 0; r < 4; ++r) {
            int row = r0 + wm + fm * 16 + (lane >> 4) * 4 + r;
            float v = x[(size_t)row * CDIM + col] + acc[fm][fn][r] + bb;
            x[(size_t)row * CDIM + col] = v;
            x_bf[(size_t)row * CDIM + col] = f2bf(v);
        }
    }
}

// final LN -> bf16
__global__ void k_lnf_bf16(const float* __restrict__ x, const float* __restrict__ g,
                           const float* __restrict__ bb, unsigned short* __restrict__ out) {
    int bi = blockIdx.x;
    int t = threadIdx.x;           // 256
    __shared__ float red[CDIM];
    float val = x[bi * CDIM + t];
    red[t] = val; __syncthreads();
    for (int s = 128; s > 0; s >>= 1) { if (t < s) red[t] += red[t + s]; __syncthreads(); }
    float mean = red[0] * (1.f / 256.f); __syncthreads();
    float dv = val - mean;
    red[t] = dv * dv; __syncthreads();
    for (int s = 128; s > 0; s >>= 1) { if (t < s) red[t] += red[t + s]; __syncthreads(); }
    float r = rsqrtf(red[0] * (1.f / 256.f) + 1e-5f);
    out[bi * CDIM + t] = f2bf(dv * r * g[t] + bb[t]);
}

// head GEMM: out[512,8000] = xf_bf @ wT^T + head_b. grid (8, 125).
__global__ __launch_bounds__(256) void k_head_mfma(
    const unsigned short* __restrict__ xf_bf,   // [512][256]
    const unsigned short* __restrict__ wT,      // [8000][256]
    const float* __restrict__ head_b,
    float* __restrict__ out)
{
    __shared__ unsigned short A_lds[64 * 128];
    __shared__ unsigned short B_lds[64 * 128];
    int t = threadIdx.x;
    int r0 = blockIdx.x * 64;
    int n0 = blockIdx.y * 64;
    f32x4 acc[2][2] = {};
    gemm64_core(xf_bf + (size_t)r0 * 256, 256, wT + (size_t)n0 * 256, 256, 256,
                t, acc, A_lds, B_lds);
    int lane = t & 63, w = t >> 6;
    int wm = (w >> 1) * 32, wn = (w & 1) * 32;
    int l15 = lane & 15;
    #pragma unroll
    for (int fm = 0; fm < 2; ++fm)
    #pragma unroll
    for (int fn = 0; fn < 2; ++fn) {
        int col = n0 + wn + fn * 16 + l15;
        float hb = head_b[col];
        #pragma unroll
        for (int r = 0; r < 4; ++r) {
            int row = r0 + wm + fm * 16 + (lane >> 4) * 4 + r;
            out[(size_t)row * NV + col] = acc[fm][fn][r] + hb;
        }
    }
}

extern "C" void kernel_launch(void* const* d_in, const int* in_sizes, int n_in,
                              void* d_out, int out_size, void* d_ws, size_t ws_size,
                              hipStream_t stream) {
    const int*   idx       = (const int*)  d_in[0];
    const float* tok_emb   = (const float*)d_in[1];
    const float* pos_table = (const float*)d_in[2];
    const float* pos_w1    = (const float*)d_in[3];
    const float* pos_w2    = (const float*)d_in[4];
    const float* pos_b2    = (const float*)d_in[5];
    const float* pos_ln_g  = (const float*)d_in[6];
    const float* pos_ln_b  = (const float*)d_in[7];
    const float* att_w1    = (const float*)d_in[8];
    const float* att_w2    = (const float*)d_in[9];
    const float* att_b2    = (const float*)d_in[10];
    const float* val_w     = (const float*)d_in[11];
    const float* proj_w    = (const float*)d_in[12];
    const float* proj_b    = (const float*)d_in[13];
    const float* ln2_g     = (const float*)d_in[14];
    const float* ln2_b     = (const float*)d_in[15];
    const float* ff_w1     = (const float*)d_in[16];
    const float* ff_w2     = (const float*)d_in[17];
    const float* ff_b2     = (const float*)d_in[18];
    const float* lnf_g     = (const float*)d_in[19];
    const float* lnf_b     = (const float*)d_in[20];
    const float* head_w    = (const float*)d_in[21];
    const float* head_b    = (const float*)d_in[22];
    float* out = (float*)d_out;

    float* ws = (float*)d_ws;
    float* x    = ws;  ws += NB * TDIM * CDIM;        // 131072
    float* PT   = ws;  ws += NB * NH * CDIM * TDIM;   // 524288
    float* Qb   = ws;  ws += NB * TDIM * NH * CDIM;   // 524288
    ws += 16;                                         // guard before RT (k_wei reads RT-3)
    float* RT   = ws;  ws += NH * CDIM * TDIM;        // 262144
    float* pbuf = PT;                                 // alias: disjoint lifetimes
    unsigned short* x_bf    = (unsigned short*)ws; ws += NB * TDIM * CDIM / 2;
    unsigned short* ped_bf  = (unsigned short*)ws; ws += TDIM * 2 * CDIM / 2;
    unsigned short* hbuf_bf = (unsigned short*)ws; ws += NB * TDIM * CDIM / 2;
    unsigned short* xf_bf   = (unsigned short*)ws; ws += NB * TDIM * CDIM / 2;
    unsigned short* wei_bf  = (unsigned short*)ws; ws += NB * NH * TDIM * TDIM / 2;
    unsigned short* vT_bf   = (unsigned short*)ws; ws += NB * NH * DHS * TDIM / 2;
    unsigned short* attn_bf = (unsigned short*)ws; ws += NB * TDIM * CDIM / 2;
    unsigned short* wT      = (unsigned short*)ws; ws += NV * CDIM / 2;
    unsigned short* W1r     = (unsigned short*)ws; ws += 2 * 1024 * 512 / 2;
    unsigned short* Wff1    = (unsigned short*)ws; ws += 2 * 1024 * 256 / 2;
    unsigned short* Wff2    = (unsigned short*)ws; ws += 2 * 256 * 1024 / 2;
    unsigned short* Wv      = (unsigned short*)ws; ws += 2 * NH * DHS * CDIM / 2;
    unsigned short* Wproj   = (unsigned short*)ws; ws += 2 * CDIM * CDIM / 2;
    unsigned short* fbuf_bf = wei_bf;                 // alias: disjoint lifetimes

    k_tcast_all<<<4304, 256, 0, stream>>>(head_w, att_w1, ff_w1, ff_w2, val_w, proj_w,
                                          wT, W1r, Wff1, Wff2, Wv, Wproj);
    k_pre<<<512, 512, 0, stream>>>(idx, tok_emb, pos_table, pos_w1, pos_w2, pos_b2,
                                   pos_ln_g, pos_ln_b, x, x_bf, ped_bf);

    for (int l = 0; l < 2; ++l) {
        k_qkv<<<352, 256, 0, stream>>>(x_bf, ped_bf, W1r, Wv, PT, Qb, RT, vT_bf, l);
        k_wei<<<NB * NH * TDIM / 4, 1024, 0, stream>>>(PT, Qb, RT, att_w2, att_b2, l, wei_bf);
        k_av_gemm<<<32, 256, 0, stream>>>(wei_bf, vT_bf, attn_bf);
        k_proj_gemm<<<32, 256, 0, stream>>>(attn_bf, Wproj, proj_b, pbuf, l);
        k_resln<<<NB * TDIM, 256, 0, stream>>>(pbuf, x, ln2_g + l * CDIM, ln2_b + l * CDIM, hbuf_bf);
        k_ff1_gemm<<<dim3(8, 16), 256, 0, stream>>>(hbuf_bf, Wff1, fbuf_bf, l);
        k_ff2_gemm<<<dim3(8, 4), 256, 0, stream>>>(fbuf_bf, Wff2, ff_b2, x, x_bf, l);
    }

    k_lnf_bf16<<<NB * TDIM, 256, 0, stream>>>(x, lnf_g, lnf_b, xf_bf);
    k_head_mfma<<<dim3(8, 125), 256, 0, stream>>>(xf_bf, wT, head_b, out);
}